// Round 14
// baseline (175.331 us; speedup 1.0000x reference)
//
#include <hip/hip_runtime.h>

// Decoder step: embed -> additive attention -> 2-layer LSTM -> fc
// Round 14: r13 (147us) + role-partitioned co-launches:
//   prep_all absorbs hproj (8 direct-f32 GEMM blocks);
//   combo_k = gates0 (640 blk) || fc ctx+emb K-segment (500 blk -> predP);
//   fc_final = fc h1 K-segment + predP + bias.
// All GEMMs: bf16 MFMA 16x16x32, LDS-staged via global_load_lds, counted
// vmcnt waits (never drained mid-loop), XOR-swizzle via pre-swizzled source.

typedef __attribute__((ext_vector_type(8))) short bf16x8;
typedef __attribute__((ext_vector_type(4))) float f32x4;

__device__ __forceinline__ short f2bf(float f){
  __bf16 h = (__bf16)f;
  return __builtin_bit_cast(short, h);
}

__device__ __forceinline__ bf16x8 cvt8(float4 a, float4 b){
  bf16x8 r;
  r[0]=f2bf(a.x); r[1]=f2bf(a.y); r[2]=f2bf(a.z); r[3]=f2bf(a.w);
  r[4]=f2bf(b.x); r[5]=f2bf(b.y); r[6]=f2bf(b.z); r[7]=f2bf(b.w);
  return r;
}

__device__ __forceinline__ bf16x8 ld8_bf(const float* __restrict__ p){
  return cvt8(*(const float4*)p, *(const float4*)(p + 4));
}

__device__ __forceinline__ float fast_tanh(float x){
  x = fminf(fmaxf(x, -15.f), 15.f);
  float t = __expf(2.f * x);
  return (t - 1.f) / (t + 1.f);
}
__device__ __forceinline__ float fast_sig(float x){
  return 1.f / (1.f + __expf(-x));
}

__device__ __forceinline__ void stage16(const void* src, void* dst_lds){
  __builtin_amdgcn_global_load_lds(
      (const __attribute__((address_space(1))) void*)src,
      (__attribute__((address_space(3))) void*)dst_lds, 16, 0, 0);
}

// ---------------------------------------------------------------------------
// Gates GEMM slice body: Pplane[64][N] = A_bf16[64, k0:k0+256] @ [W1|W2]^T.
// smem: 32 KB A + 48 KB W (3-buffer rotation).
// ---------------------------------------------------------------------------
__device__ __forceinline__ void gates_body(
    const short* __restrict__ A, int lda,
    const float* __restrict__ W1, int sW1, int K1,
    const float* __restrict__ W2, int sW2,
    float* __restrict__ Pplane, int N, int nb, int k0, char* smem)
{
  short* Al = (short*)smem;             // 32 KB
  float* Wl = (float*)(smem + 32768);   // 3 x 16 KB
  const int wv   = threadIdx.x >> 6;
  const int lane = threadIdx.x & 63;
  const int l15  = lane & 15;
  const int lg   = lane >> 4;

  const float* W; int sW, koff;
  if (k0 < K1){ W = W1; sW = sW1; koff = k0; }
  else        { W = W2; sW = sW2; koff = k0 - K1; }

  {
    const int r2  = lane >> 5;
    const int c16 = (lane & 31) * 16;
    #pragma unroll
    for (int i = 0; i < 8; ++i){
      int rbase = wv*16 + i*2;
      int row   = rbase + r2;
      const char* src = (const char*)A + (long)row*lda*2 + (long)k0*2
                        + (c16 ^ ((row & 7) << 4));
      stage16(src, (void*)(Al + rbase*256));
    }
  }

  auto STAGEW = [&](int bi, int kbase){
    #pragma unroll
    for (int i = 0; i < 4; ++i){
      int row = wv*16 + i*4 + lg;
      const char* src = (const char*)(W + (long)(nb + row)*sW + koff + kbase)
                        + ((l15*16) ^ ((row & 7) << 4));
      stage16(src, (void*)(Wl + bi*4096 + (wv*16 + i*4)*64));
    }
  };

  STAGEW(0, 0);
  STAGEW(1, 64);
  asm volatile("s_waitcnt vmcnt(8)" ::: "memory");
  asm volatile("s_barrier" ::: "memory");

  f32x4 acc[4];
  #pragma unroll
  for (int m = 0; m < 4; ++m) acc[m] = (f32x4){0.f,0.f,0.f,0.f};

  const int  rl = wv*16 + l15;
  const int  sw = (l15 & 7) << 4;
  const char* wbase = (const char*)Wl;
  const char* abase = (const char*)Al;

  auto COMPUTE = [&](int bi, int t){
    bf16x8 a[4][2];
    #pragma unroll
    for (int m = 0; m < 4; ++m)
      #pragma unroll
      for (int h = 0; h < 2; ++h){
        int cb = t*128 + h*64 + lg*16;
        a[m][h] = *(const bf16x8*)(abase + (m*16 + l15)*512 + (cb ^ sw));
      }
    const char* rb = wbase + bi*16384 + rl*256;
    float4 w00 = *(const float4*)(rb + ((lg*32      ) ^ sw));
    float4 w01 = *(const float4*)(rb + ((lg*32 + 16 ) ^ sw));
    float4 w10 = *(const float4*)(rb + ((lg*32 + 128) ^ sw));
    float4 w11 = *(const float4*)(rb + ((lg*32 + 144) ^ sw));
    bf16x8 wf0 = cvt8(w00, w01);
    bf16x8 wf1 = cvt8(w10, w11);
    #pragma unroll
    for (int m = 0; m < 4; ++m)
      acc[m] = __builtin_amdgcn_mfma_f32_16x16x32_bf16(a[m][0], wf0, acc[m], 0,0,0);
    #pragma unroll
    for (int m = 0; m < 4; ++m)
      acc[m] = __builtin_amdgcn_mfma_f32_16x16x32_bf16(a[m][1], wf1, acc[m], 0,0,0);
  };

  asm volatile("s_waitcnt vmcnt(4)" ::: "memory");
  COMPUTE(0, 0);
  STAGEW(2, 128);
  asm volatile("s_waitcnt vmcnt(4)" ::: "memory");
  COMPUTE(1, 1);
  STAGEW(0, 192);
  asm volatile("s_waitcnt vmcnt(4)" ::: "memory");
  COMPUTE(2, 2);
  asm volatile("s_waitcnt vmcnt(0)" ::: "memory");
  COMPUTE(0, 3);

  #pragma unroll
  for (int mt = 0; mt < 4; ++mt)
    #pragma unroll
    for (int r = 0; r < 4; ++r){
      int m = mt*16 + lg*4 + r;
      Pplane[(long)m * N + nb + wv*16 + l15] = acc[mt][r];
    }
}

// ---------------------------------------------------------------------------
// fc GEMM body: C[64, nb:nb+64] = A[64, 0:NC*128] @ W^T (+ addsrc + bias).
// smem: 2x16 KB A double-buffer + 3x16 KB W rotation. NC = K/128.
// ---------------------------------------------------------------------------
__device__ __forceinline__ void fc_body(
    const short* __restrict__ A, int lda,
    const float* __restrict__ W, int sW, int NC,
    const float* __restrict__ addsrc, const float* __restrict__ bias,
    float* __restrict__ C, int N, int nb, char* smem)
{
  short* Al = (short*)smem;             // 2 x 16 KB
  float* Wl = (float*)(smem + 32768);   // 3 x 16 KB
  const int wv   = threadIdx.x >> 6;
  const int lane = threadIdx.x & 63;
  const int l15  = lane & 15;
  const int lg   = lane >> 4;

  auto STAGEA = [&](int c){
    short* dst = Al + (c & 1) * 8192;
    #pragma unroll
    for (int i = 0; i < 4; ++i){
      int rbase = wv*16 + i*4;
      int row   = rbase + lg;
      const char* src = (const char*)(A + (long)row*lda + c*128)
                        + ((l15*16) ^ ((row & 7) << 4));
      stage16(src, (void*)(dst + rbase*128));
    }
  };
  auto STAGEW = [&](int s){
    float* dst = Wl + (s % 3) * 4096;
    #pragma unroll
    for (int i = 0; i < 4; ++i){
      int row = wv*16 + i*4 + lg;
      const char* src = (const char*)(W + (long)(nb + row)*sW + s*64)
                        + ((l15*16) ^ ((row & 7) << 4));
      stage16(src, (void*)(dst + (wv*16 + i*4)*64));
    }
  };

  f32x4 acc[4];
  #pragma unroll
  for (int m = 0; m < 4; ++m) acc[m] = (f32x4){0.f,0.f,0.f,0.f};

  const int rl = wv*16 + l15;
  const int sw = (l15 & 7) << 4;

  auto COMPUTE = [&](int s){
    const char* abase = (const char*)(Al + ((s >> 1) & 1) * 8192);
    const int   kh    = (s & 1) * 128;
    bf16x8 a[4][2];
    #pragma unroll
    for (int m = 0; m < 4; ++m)
      #pragma unroll
      for (int h = 0; h < 2; ++h){
        int cb = kh + h*64 + lg*16;
        a[m][h] = *(const bf16x8*)(abase + (m*16 + l15)*256 + (cb ^ sw));
      }
    const char* rb = (const char*)(Wl + (s % 3)*4096) + rl*256;
    float4 w00 = *(const float4*)(rb + ((lg*32      ) ^ sw));
    float4 w01 = *(const float4*)(rb + ((lg*32 + 16 ) ^ sw));
    float4 w10 = *(const float4*)(rb + ((lg*32 + 128) ^ sw));
    float4 w11 = *(const float4*)(rb + ((lg*32 + 144) ^ sw));
    bf16x8 wf0 = cvt8(w00, w01);
    bf16x8 wf1 = cvt8(w10, w11);
    #pragma unroll
    for (int m = 0; m < 4; ++m)
      acc[m] = __builtin_amdgcn_mfma_f32_16x16x32_bf16(a[m][0], wf0, acc[m], 0,0,0);
    #pragma unroll
    for (int m = 0; m < 4; ++m)
      acc[m] = __builtin_amdgcn_mfma_f32_16x16x32_bf16(a[m][1], wf1, acc[m], 0,0,0);
  };

  STAGEA(0); STAGEW(0); STAGEW(1);
  asm volatile("s_waitcnt vmcnt(4)" ::: "memory");
  __builtin_amdgcn_s_barrier();

  STAGEA(1);
  COMPUTE(0);
  STAGEW(2);
  asm volatile("s_waitcnt vmcnt(4)" ::: "memory");
  COMPUTE(1);
  STAGEW(3);
  __builtin_amdgcn_s_barrier();

  for (int c = 1; c < NC-1; ++c){
    STAGEA(c+1);
    asm volatile("s_waitcnt vmcnt(8)" ::: "memory");
    COMPUTE(2*c);
    STAGEW(2*c+2);
    asm volatile("s_waitcnt vmcnt(4)" ::: "memory");
    COMPUTE(2*c+1);
    STAGEW(2*c+3);
    __builtin_amdgcn_s_barrier();
  }

  asm volatile("s_waitcnt vmcnt(4)" ::: "memory");
  COMPUTE(2*NC-2);
  asm volatile("s_waitcnt vmcnt(0)" ::: "memory");
  COMPUTE(2*NC-1);

  const int col = nb + wv*16 + l15;
  const float bn = bias ? bias[col] : 0.f;
  #pragma unroll
  for (int mt = 0; mt < 4; ++mt)
    #pragma unroll
    for (int r = 0; r < 4; ++r){
      int m = mt*16 + lg*4 + r;
      long idx = (long)m * N + col;
      float v = acc[mt][r] + bn;
      if (addsrc) v += addsrc[idx];
      C[idx] = v;
    }
}

// ---------------------------------------------------------------------------
// Fused prep: [0,8) hproj GEMM (direct f32 reads, +attn_b -> hpr),
// [8,4104) enc->bf16, [4104,4360) attn_w cvt, [4360,4376) emb gather,
// [4376,4408) hidden cvt, [4408,4412) scores zero.
// ---------------------------------------------------------------------------
__global__ __launch_bounds__(256) void prep_all(
    const int* __restrict__ tok, const float* __restrict__ emb,
    const float* __restrict__ hidden, const float* __restrict__ enc,
    const float* __restrict__ attn_w, const float* __restrict__ attn_b,
    short* __restrict__ encbf, short* __restrict__ Wbf,
    short* __restrict__ A0, short* __restrict__ A1, short* __restrict__ Zb,
    float* __restrict__ sco, float* __restrict__ hpr)
{
  const int bid = blockIdx.x, t = threadIdx.x;
  if (bid < 8){
    const int wv = t >> 6, lane = t & 63, l15 = lane & 15, lg = lane >> 4;
    const int nb = bid*64 + wv*16;
    const float* hrow = hidden + 65536;            // h_top [64][1024] f32
    const float* wrow = attn_w + (long)(nb + l15)*2048 + lg*8;
    f32x4 acc[4] = {};
    bf16x8 wn  = ld8_bf(wrow);
    bf16x8 an0 = ld8_bf(hrow + l15*1024 + lg*8);
    bf16x8 an1 = ld8_bf(hrow + (16+l15)*1024 + lg*8);
    bf16x8 an2 = ld8_bf(hrow + (32+l15)*1024 + lg*8);
    bf16x8 an3 = ld8_bf(hrow + (48+l15)*1024 + lg*8);
    for (int kb = 32; kb < 1024; kb += 32){
      bf16x8 wc = wn, c0 = an0, c1 = an1, c2 = an2, c3 = an3;
      wn  = ld8_bf(wrow + kb);
      an0 = ld8_bf(hrow + l15*1024 + lg*8 + kb);
      an1 = ld8_bf(hrow + (16+l15)*1024 + lg*8 + kb);
      an2 = ld8_bf(hrow + (32+l15)*1024 + lg*8 + kb);
      an3 = ld8_bf(hrow + (48+l15)*1024 + lg*8 + kb);
      acc[0] = __builtin_amdgcn_mfma_f32_16x16x32_bf16(c0, wc, acc[0], 0,0,0);
      acc[1] = __builtin_amdgcn_mfma_f32_16x16x32_bf16(c1, wc, acc[1], 0,0,0);
      acc[2] = __builtin_amdgcn_mfma_f32_16x16x32_bf16(c2, wc, acc[2], 0,0,0);
      acc[3] = __builtin_amdgcn_mfma_f32_16x16x32_bf16(c3, wc, acc[3], 0,0,0);
    }
    acc[0] = __builtin_amdgcn_mfma_f32_16x16x32_bf16(an0, wn, acc[0], 0,0,0);
    acc[1] = __builtin_amdgcn_mfma_f32_16x16x32_bf16(an1, wn, acc[1], 0,0,0);
    acc[2] = __builtin_amdgcn_mfma_f32_16x16x32_bf16(an2, wn, acc[2], 0,0,0);
    acc[3] = __builtin_amdgcn_mfma_f32_16x16x32_bf16(an3, wn, acc[3], 0,0,0);
    const float bn = attn_b[nb + l15];
    #pragma unroll
    for (int mt = 0; mt < 4; ++mt)
      #pragma unroll
      for (int r = 0; r < 4; ++r)
        hpr[(mt*16 + lg*4 + r)*512 + nb + l15] = acc[mt][r] + bn;
  } else if (bid < 4104){
    long i = ((long)(bid-8)*256 + t)*8;
    *(bf16x8*)(encbf + i) = ld8_bf(enc + i);
  } else if (bid < 4360){
    int j = (bid-4104)*256 + t;
    int r = j >> 7, c = (j & 127)*8;
    *(bf16x8*)(Wbf + r*1024 + c) = ld8_bf(attn_w + (long)r*2048 + 1024 + c);
  } else if (bid < 4376){
    int j = (bid-4360)*256 + t;
    int b = j >> 6, e8 = (j & 63)*8;
    bf16x8 v = ld8_bf(emb + (long)tok[b]*512 + e8);
    *(bf16x8*)(A0 + b*2560 + e8) = v;
    *(bf16x8*)(Zb + b*2560 + 2048 + e8) = v;
  } else if (bid < 4408){
    int j = (bid-4376)*256 + t;
    int b = j >> 7, n8 = (j & 127)*8;
    *(bf16x8*)(A0 + b*2560 + 1536 + n8) = ld8_bf(hidden + (long)b*1024 + n8);
    *(bf16x8*)(A1 + b*2048 + 1024 + n8) = ld8_bf(hidden + 65536 + (long)b*1024 + n8);
  } else {
    int j = (bid-4408)*256 + t;
    float4 z = {0.f, 0.f, 0.f, 0.f};
    *(float4*)(sco + j*8) = z;
    *(float4*)(sco + j*8 + 4) = z;
  }
}

// ---------------------------------------------------------------------------
// energy: T = encbf @ Wbf^T ; scores += v.tanh(T + hpr). Both operands
// streamed to LDS in 64-k chunks, 3-buffer rotation, counted vmcnt(4).
// grid 1024: m3 = bx&127 -> n-blocks of an m-tile share an XCD L2.
// ---------------------------------------------------------------------------
__global__ __launch_bounds__(256) void energy_lds(
    const short* __restrict__ encbf, const short* __restrict__ Wbf,
    const float* __restrict__ hpr, const float* __restrict__ v_w,
    float* __restrict__ scores)
{
  __shared__ short Ab[3][64*64];   // enc chunks, 24 KB
  __shared__ short Bb[3][64*64];   // Wbf chunks, 24 KB
  const int bx   = blockIdx.x;
  const int m3   = bx & 127, n3 = bx >> 7;
  const int wv   = threadIdx.x >> 6;
  const int lane = threadIdx.x & 63;
  const int l15  = lane & 15;
  const int lg   = lane >> 4;
  const int mb   = m3 * 64;
  const int nbg  = n3 * 64;
  const int nb   = nbg + wv * 16;
  const int b    = mb >> 7;

  const float hp = hpr[(long)b*512 + nb + l15];
  const float vn = v_w[nb + l15];

  const int srow = lane >> 3;
  const int scb  = (lane & 7) * 16;

  auto STAGE = [&](int c, int kb){
    short* da = Ab[c % 3];
    short* db = Bb[c % 3];
    #pragma unroll
    for (int i = 0; i < 2; ++i){
      int rbase = wv*16 + i*8;
      int row   = rbase + srow;
      int swz   = scb ^ ((row & 7) << 4);
      const char* sa = (const char*)(encbf + (long)(mb + row)*1024 + kb) + swz;
      stage16(sa, (void*)(da + rbase*64));
      const char* sb = (const char*)(Wbf + (long)(nbg + row)*1024 + kb) + swz;
      stage16(sb, (void*)(db + rbase*64));
    }
  };

  f32x4 acc[4] = {};
  const int brow = wv*16 + l15;
  const int bswz = (brow & 7) << 4;
  const int aswz = (l15 & 7) << 4;

  auto COMPUTE = [&](int c){
    const char* ab = (const char*)Ab[c % 3];
    const char* bb = (const char*)Bb[c % 3];
    #pragma unroll
    for (int h = 0; h < 2; ++h){
      const int colb = h*64 + lg*16;
      bf16x8 bf_ = *(const bf16x8*)(bb + brow*128 + (colb ^ bswz));
      #pragma unroll
      for (int m = 0; m < 4; ++m){
        const int arow = m*16 + l15;
        bf16x8 af = *(const bf16x8*)(ab + arow*128 + (colb ^ aswz));
        acc[m] = __builtin_amdgcn_mfma_f32_16x16x32_bf16(af, bf_, acc[m], 0,0,0);
      }
    }
  };

  STAGE(0, 0);
  STAGE(1, 64);
  for (int c = 0; c < 14; ++c){
    asm volatile("s_waitcnt vmcnt(4)" ::: "memory");
    __builtin_amdgcn_s_barrier();
    COMPUTE(c);
    STAGE(c+2, (c+2)*64);
  }
  asm volatile("s_waitcnt vmcnt(4)" ::: "memory");
  __builtin_amdgcn_s_barrier();
  COMPUTE(14);
  asm volatile("s_waitcnt vmcnt(0)" ::: "memory");
  __builtin_amdgcn_s_barrier();
  COMPUTE(15);

  #pragma unroll
  for (int mt = 0; mt < 4; ++mt){
    #pragma unroll
    for (int r = 0; r < 4; ++r){
      int m = mb + mt*16 + lg*4 + r;
      float e = fast_tanh(acc[mt][r] + hp) * vn;
      e += __shfl_xor(e, 1, 16);
      e += __shfl_xor(e, 2, 16);
      e += __shfl_xor(e, 4, 16);
      e += __shfl_xor(e, 8, 16);
      if (l15 == 0) atomicAdd(&scores[m], e);
    }
  }
}

// Fused masked softmax + context (ILP: 4 accumulators)
__global__ __launch_bounds__(256) void ctxsm_k(
    const float* __restrict__ sco, const int* __restrict__ mask,
    const short* __restrict__ encbf, float* __restrict__ aw,
    short* __restrict__ A0, short* __restrict__ Zb)
{
  const int bb = blockIdx.x;
  const int t  = threadIdx.x;
  __shared__ float red[128];
  __shared__ float w[128];
  float v = 0.f;
  if (t < 128){
    v = sco[bb*128 + t];
    if (mask[bb*128 + t] == 0) v = -1e10f;
    red[t] = v;
  }
  __syncthreads();
  for (int d = 64; d > 0; d >>= 1){
    if (t < d) red[t] = fmaxf(red[t], red[t + d]);
    __syncthreads();
  }
  const float mx = red[0];
  __syncthreads();
  if (t < 128){
    float e = __expf(v - mx);
    w[t] = e; red[t] = e;
  }
  __syncthreads();
  for (int d = 64; d > 0; d >>= 1){
    if (t < d) red[t] += red[t + d];
    __syncthreads();
  }
  const float inv = 1.f / red[0];
  if (blockIdx.y == 0 && t < 128) aw[bb*128 + t] = w[t] * inv;

  const int dd = blockIdx.y * 256 + t;
  const unsigned short* e = (const unsigned short*)encbf + (long)bb*131072 + dd;
  float s0 = 0.f, s1 = 0.f, s2 = 0.f, s3 = 0.f;
  #pragma unroll 8
  for (int si = 0; si < 128; si += 4){
    s0 += w[si  ] * __builtin_bit_cast(float, (unsigned)e[(si  )*1024] << 16);
    s1 += w[si+1] * __builtin_bit_cast(float, (unsigned)e[(si+1)*1024] << 16);
    s2 += w[si+2] * __builtin_bit_cast(float, (unsigned)e[(si+2)*1024] << 16);
    s3 += w[si+3] * __builtin_bit_cast(float, (unsigned)e[(si+3)*1024] << 16);
  }
  float s = ((s0 + s1) + (s2 + s3)) * inv;
  short vbf = f2bf(s);
  A0[bb*2560 + 512  + dd] = vbf;
  Zb[bb*2560 + 1024 + dd] = vbf;
}

// standalone gates GEMM (gates1)
__global__ __launch_bounds__(256) void gemm_lds(
    const short* __restrict__ A, int lda,
    const float* __restrict__ W1, int sW1, int K1,
    const float* __restrict__ W2, int sW2,
    float* __restrict__ P, int N)
{
  __shared__ char smem[81920];
  gates_body(A, lda, W1, sW1, K1, W2, sW2,
             P + (long)blockIdx.y * 64 * N, N,
             blockIdx.x * 64, blockIdx.y * 256, smem);
}

// combo: [0,500) fc ctx+emb K-segment -> predP ; [500,1140) gates0 slices
__global__ __launch_bounds__(256) void combo_k(
    const short* __restrict__ A0, const float* __restrict__ w_ih0,
    const float* __restrict__ w_hh0, float* __restrict__ Pb,
    const short* __restrict__ Zb, const float* __restrict__ fc_w,
    float* __restrict__ predP)
{
  __shared__ char smem[81920];
  if (blockIdx.x < 500){
    fc_body(Zb + 1024, 2560, fc_w + 1024, 2560, 12, nullptr, nullptr,
            predP, 32000, blockIdx.x * 64, smem);
  } else {
    int b2 = blockIdx.x - 500;
    gates_body(A0, 2560, w_ih0, 1536, 1536, w_hh0, 1024,
               Pb + (long)(b2 >> 6) * 262144, 4096,
               (b2 & 63) * 64, (b2 >> 6) * 256, smem);
  }
}

// fc final: K 0..1024 + predP + bias
__global__ __launch_bounds__(256) void fc_final(
    const short* __restrict__ Zb, const float* __restrict__ fc_w,
    const float* __restrict__ predP, const float* __restrict__ fc_b,
    float* __restrict__ pred)
{
  __shared__ char smem[81920];
  fc_body(Zb, 2560, fc_w, 2560, 8, predP, fc_b, pred, 32000,
          blockIdx.x * 64, smem);
}

// LSTM epilogue with fused split-K reduce (KS templated)
template<int KS>
__global__ __launch_bounds__(256) void lstm_k(
    const float* __restrict__ P,
    const float* __restrict__ bi, const float* __restrict__ bh,
    const float* __restrict__ c_prev,
    float* __restrict__ h_out, float* __restrict__ c_out,
    short* __restrict__ h_bf, int bf_stride)
{
  const int i = blockIdx.x * 256 + threadIdx.x;
  const int b = i >> 10, n = i & 1023;
  float g4[4];
  #pragma unroll
  for (int gi = 0; gi < 4; ++gi){
    int col = gi*1024 + n;
    float s = bi[col] + bh[col];
    const float* p = P + (long)b*4096 + col;
    #pragma unroll
    for (int sl = 0; sl < KS; ++sl) s += p[(long)sl * 262144];
    g4[gi] = s;
  }
  float iv = fast_sig (g4[0]);
  float fv = fast_sig (g4[1]);
  float gv = fast_tanh(g4[2]);
  float ov = fast_sig (g4[3]);
  float c = fv * c_prev[i] + iv * gv;
  float h = ov * fast_tanh(c);
  c_out[i] = c;
  h_out[i] = h;
  h_bf[(long)b * bf_stride + n] = f2bf(h);
}

extern "C" void kernel_launch(void* const* d_in, const int* in_sizes, int n_in,
                              void* d_out, int out_size, void* d_ws, size_t ws_size,
                              hipStream_t stream)
{
  const int*   tok    = (const int*)  d_in[0];
  const float* hidden = (const float*)d_in[1];
  const float* cell   = (const float*)d_in[2];
  const float* enc    = (const float*)d_in[3];
  const int*   mask   = (const int*)  d_in[4];
  const float* emb    = (const float*)d_in[5];
  const float* attn_w = (const float*)d_in[6];
  const float* attn_b = (const float*)d_in[7];
  const float* v_w    = (const float*)d_in[8];
  const float* w_ih0  = (const float*)d_in[9];
  const float* w_hh0  = (const float*)d_in[10];
  const float* b_ih0  = (const float*)d_in[11];
  const float* b_hh0  = (const float*)d_in[12];
  const float* w_ih1  = (const float*)d_in[13];
  const float* w_hh1  = (const float*)d_in[14];
  const float* b_ih1  = (const float*)d_in[15];
  const float* b_hh1  = (const float*)d_in[16];
  const float* fc_w   = (const float*)d_in[17];
  const float* fc_b   = (const float*)d_in[18];

  float* out  = (float*)d_out;
  float* pred = out;                 // [64,32000]
  float* nh   = out + 2048000;       // [2,64,1024]
  float* nc   = out + 2179072;       // [2,64,1024]
  float* aw   = out + 2310144;       // [64,128]

  char*  wsb   = (char*)d_ws;
  short* encbf = (short*)(wsb + 0);          // 16,777,216 B
  short* Wbf   = (short*)(wsb + 16777216);   //  1,048,576 B
  short* A0    = (short*)(wsb + 17825792);   //    327,680 B
  short* A1    = (short*)(wsb + 18153472);   //    262,144 B
  short* Zb    = (short*)(wsb + 18415616);   //    327,680 B
  float* sco   = (float*)(wsb + 18743296);   //     32,768 B
  float* hpr   = (float*)(wsb + 18776064);   //    131,072 B
  float* Pb    = (float*)(wsb + 18907136);   // 10,485,760 B (10 gate planes)
  float* predP = (float*)(wsb + 29392896);   //  8,192,000 B

  prep_all<<<4412, 256, 0, stream>>>(tok, emb, hidden, enc, attn_w, attn_b,
                                     encbf, Wbf, A0, A1, Zb, sco, hpr);

  energy_lds<<<1024, 256, 0, stream>>>(encbf, Wbf, hpr, v_w, sco);

  ctxsm_k<<<dim3(64, 4), 256, 0, stream>>>(sco, mask, encbf, aw, A0, Zb);

  // gates0 (10 slices) || fc ctx+emb segment (K=1024..2560) -> predP
  combo_k<<<1140, 256, 0, stream>>>(A0, w_ih0, w_hh0, Pb, Zb, fc_w, predP);

  lstm_k<10><<<256, 256, 0, stream>>>(Pb, b_ih0, b_hh0, cell,
                                      nh, nc, A1, 2048);

  // layer 1: A1 = [h0' | h1_prev], W = [w_ih1 | w_hh1], K=2048
  gemm_lds<<<dim3(64, 8), 256, 0, stream>>>(A1, 2048,
                                            w_ih1, 1024, 1024, w_hh1, 1024,
                                            Pb, 4096);
  lstm_k<8><<<256, 256, 0, stream>>>(Pb, b_ih1, b_hh1, cell + 65536,
                                     nh + 65536, nc + 65536, Zb, 2560);

  // prediction: fc h1 segment (K=0..1024) + predP + fc_b
  fc_final<<<500, 256, 0, stream>>>(Zb, fc_w, predP, fc_b, pred);
}

// Round 15
// 169.732 us; speedup vs baseline: 1.0330x; 1.0330x over previous
//
#include <hip/hip_runtime.h>

// Decoder step: embed -> additive attention -> 2-layer LSTM -> fc
// Round 15: r13 (147us) + balanced consolidations:
//   prep_all absorbs hproj (8 GEMM blocks);
//   gates01_k = gates0 (640 blk -> Pb) || gates1 hidden-half (256 blk -> Pb1
//     planes 4..7, depends only on prep) -- balanced per-block work;
//   gates1a = remaining 4 slices (k<1024, needs h0') -> Pb1 planes 0..3.
// All GEMMs: bf16 MFMA 16x16x32, LDS-staged via global_load_lds, counted
// vmcnt waits (never drained mid-loop), XOR-swizzle via pre-swizzled source.

typedef __attribute__((ext_vector_type(8))) short bf16x8;
typedef __attribute__((ext_vector_type(4))) float f32x4;

__device__ __forceinline__ short f2bf(float f){
  __bf16 h = (__bf16)f;
  return __builtin_bit_cast(short, h);
}

__device__ __forceinline__ bf16x8 cvt8(float4 a, float4 b){
  bf16x8 r;
  r[0]=f2bf(a.x); r[1]=f2bf(a.y); r[2]=f2bf(a.z); r[3]=f2bf(a.w);
  r[4]=f2bf(b.x); r[5]=f2bf(b.y); r[6]=f2bf(b.z); r[7]=f2bf(b.w);
  return r;
}

__device__ __forceinline__ bf16x8 ld8_bf(const float* __restrict__ p){
  return cvt8(*(const float4*)p, *(const float4*)(p + 4));
}

__device__ __forceinline__ float fast_tanh(float x){
  x = fminf(fmaxf(x, -15.f), 15.f);
  float t = __expf(2.f * x);
  return (t - 1.f) / (t + 1.f);
}
__device__ __forceinline__ float fast_sig(float x){
  return 1.f / (1.f + __expf(-x));
}

__device__ __forceinline__ void stage16(const void* src, void* dst_lds){
  __builtin_amdgcn_global_load_lds(
      (const __attribute__((address_space(1))) void*)src,
      (__attribute__((address_space(3))) void*)dst_lds, 16, 0, 0);
}

// ---------------------------------------------------------------------------
// Gates GEMM slice body: Pplane[64][N] = A_bf16[64, k0:k0+256] @ [W1|W2]^T.
// smem: 32 KB A + 48 KB W (3-buffer rotation).
// ---------------------------------------------------------------------------
__device__ __forceinline__ void gates_body(
    const short* __restrict__ A, int lda,
    const float* __restrict__ W1, int sW1, int K1,
    const float* __restrict__ W2, int sW2,
    float* __restrict__ Pplane, int N, int nb, int k0, char* smem)
{
  short* Al = (short*)smem;             // 32 KB
  float* Wl = (float*)(smem + 32768);   // 3 x 16 KB
  const int wv   = threadIdx.x >> 6;
  const int lane = threadIdx.x & 63;
  const int l15  = lane & 15;
  const int lg   = lane >> 4;

  const float* W; int sW, koff;
  if (k0 < K1){ W = W1; sW = sW1; koff = k0; }
  else        { W = W2; sW = sW2; koff = k0 - K1; }

  {
    const int r2  = lane >> 5;
    const int c16 = (lane & 31) * 16;
    #pragma unroll
    for (int i = 0; i < 8; ++i){
      int rbase = wv*16 + i*2;
      int row   = rbase + r2;
      const char* src = (const char*)A + (long)row*lda*2 + (long)k0*2
                        + (c16 ^ ((row & 7) << 4));
      stage16(src, (void*)(Al + rbase*256));
    }
  }

  auto STAGEW = [&](int bi, int kbase){
    #pragma unroll
    for (int i = 0; i < 4; ++i){
      int row = wv*16 + i*4 + lg;
      const char* src = (const char*)(W + (long)(nb + row)*sW + koff + kbase)
                        + ((l15*16) ^ ((row & 7) << 4));
      stage16(src, (void*)(Wl + bi*4096 + (wv*16 + i*4)*64));
    }
  };

  STAGEW(0, 0);
  STAGEW(1, 64);
  asm volatile("s_waitcnt vmcnt(8)" ::: "memory");
  asm volatile("s_barrier" ::: "memory");

  f32x4 acc[4];
  #pragma unroll
  for (int m = 0; m < 4; ++m) acc[m] = (f32x4){0.f,0.f,0.f,0.f};

  const int  rl = wv*16 + l15;
  const int  sw = (l15 & 7) << 4;
  const char* wbase = (const char*)Wl;
  const char* abase = (const char*)Al;

  auto COMPUTE = [&](int bi, int t){
    bf16x8 a[4][2];
    #pragma unroll
    for (int m = 0; m < 4; ++m)
      #pragma unroll
      for (int h = 0; h < 2; ++h){
        int cb = t*128 + h*64 + lg*16;
        a[m][h] = *(const bf16x8*)(abase + (m*16 + l15)*512 + (cb ^ sw));
      }
    const char* rb = wbase + bi*16384 + rl*256;
    float4 w00 = *(const float4*)(rb + ((lg*32      ) ^ sw));
    float4 w01 = *(const float4*)(rb + ((lg*32 + 16 ) ^ sw));
    float4 w10 = *(const float4*)(rb + ((lg*32 + 128) ^ sw));
    float4 w11 = *(const float4*)(rb + ((lg*32 + 144) ^ sw));
    bf16x8 wf0 = cvt8(w00, w01);
    bf16x8 wf1 = cvt8(w10, w11);
    #pragma unroll
    for (int m = 0; m < 4; ++m)
      acc[m] = __builtin_amdgcn_mfma_f32_16x16x32_bf16(a[m][0], wf0, acc[m], 0,0,0);
    #pragma unroll
    for (int m = 0; m < 4; ++m)
      acc[m] = __builtin_amdgcn_mfma_f32_16x16x32_bf16(a[m][1], wf1, acc[m], 0,0,0);
  };

  asm volatile("s_waitcnt vmcnt(4)" ::: "memory");
  COMPUTE(0, 0);
  STAGEW(2, 128);
  asm volatile("s_waitcnt vmcnt(4)" ::: "memory");
  COMPUTE(1, 1);
  STAGEW(0, 192);
  asm volatile("s_waitcnt vmcnt(4)" ::: "memory");
  COMPUTE(2, 2);
  asm volatile("s_waitcnt vmcnt(0)" ::: "memory");
  COMPUTE(0, 3);

  #pragma unroll
  for (int mt = 0; mt < 4; ++mt)
    #pragma unroll
    for (int r = 0; r < 4; ++r){
      int m = mt*16 + lg*4 + r;
      Pplane[(long)m * N + nb + wv*16 + l15] = acc[mt][r];
    }
}

// ---------------------------------------------------------------------------
// fc GEMM body: C[64, nb:nb+64] = A[64, 0:NC*128] @ W^T + bias.
// smem: 2x16 KB A double-buffer + 3x16 KB W rotation. NC = K/128.
// ---------------------------------------------------------------------------
__device__ __forceinline__ void fc_body(
    const short* __restrict__ A, int lda,
    const float* __restrict__ W, int sW, int NC,
    const float* __restrict__ bias,
    float* __restrict__ C, int N, int nb, char* smem)
{
  short* Al = (short*)smem;             // 2 x 16 KB
  float* Wl = (float*)(smem + 32768);   // 3 x 16 KB
  const int wv   = threadIdx.x >> 6;
  const int lane = threadIdx.x & 63;
  const int l15  = lane & 15;
  const int lg   = lane >> 4;

  auto STAGEA = [&](int c){
    short* dst = Al + (c & 1) * 8192;
    #pragma unroll
    for (int i = 0; i < 4; ++i){
      int rbase = wv*16 + i*4;
      int row   = rbase + lg;
      const char* src = (const char*)(A + (long)row*lda + c*128)
                        + ((l15*16) ^ ((row & 7) << 4));
      stage16(src, (void*)(dst + rbase*128));
    }
  };
  auto STAGEW = [&](int s){
    float* dst = Wl + (s % 3) * 4096;
    #pragma unroll
    for (int i = 0; i < 4; ++i){
      int row = wv*16 + i*4 + lg;
      const char* src = (const char*)(W + (long)(nb + row)*sW + s*64)
                        + ((l15*16) ^ ((row & 7) << 4));
      stage16(src, (void*)(dst + (wv*16 + i*4)*64));
    }
  };

  f32x4 acc[4];
  #pragma unroll
  for (int m = 0; m < 4; ++m) acc[m] = (f32x4){0.f,0.f,0.f,0.f};

  const int rl = wv*16 + l15;
  const int sw = (l15 & 7) << 4;

  auto COMPUTE = [&](int s){
    const char* abase = (const char*)(Al + ((s >> 1) & 1) * 8192);
    const int   kh    = (s & 1) * 128;
    bf16x8 a[4][2];
    #pragma unroll
    for (int m = 0; m < 4; ++m)
      #pragma unroll
      for (int h = 0; h < 2; ++h){
        int cb = kh + h*64 + lg*16;
        a[m][h] = *(const bf16x8*)(abase + (m*16 + l15)*256 + (cb ^ sw));
      }
    const char* rb = (const char*)(Wl + (s % 3)*4096) + rl*256;
    float4 w00 = *(const float4*)(rb + ((lg*32      ) ^ sw));
    float4 w01 = *(const float4*)(rb + ((lg*32 + 16 ) ^ sw));
    float4 w10 = *(const float4*)(rb + ((lg*32 + 128) ^ sw));
    float4 w11 = *(const float4*)(rb + ((lg*32 + 144) ^ sw));
    bf16x8 wf0 = cvt8(w00, w01);
    bf16x8 wf1 = cvt8(w10, w11);
    #pragma unroll
    for (int m = 0; m < 4; ++m)
      acc[m] = __builtin_amdgcn_mfma_f32_16x16x32_bf16(a[m][0], wf0, acc[m], 0,0,0);
    #pragma unroll
    for (int m = 0; m < 4; ++m)
      acc[m] = __builtin_amdgcn_mfma_f32_16x16x32_bf16(a[m][1], wf1, acc[m], 0,0,0);
  };

  STAGEA(0); STAGEW(0); STAGEW(1);
  asm volatile("s_waitcnt vmcnt(4)" ::: "memory");
  __builtin_amdgcn_s_barrier();

  STAGEA(1);
  COMPUTE(0);
  STAGEW(2);
  asm volatile("s_waitcnt vmcnt(4)" ::: "memory");
  COMPUTE(1);
  STAGEW(3);
  __builtin_amdgcn_s_barrier();

  for (int c = 1; c < NC-1; ++c){
    STAGEA(c+1);
    asm volatile("s_waitcnt vmcnt(8)" ::: "memory");
    COMPUTE(2*c);
    STAGEW(2*c+2);
    asm volatile("s_waitcnt vmcnt(4)" ::: "memory");
    COMPUTE(2*c+1);
    STAGEW(2*c+3);
    __builtin_amdgcn_s_barrier();
  }

  asm volatile("s_waitcnt vmcnt(4)" ::: "memory");
  COMPUTE(2*NC-2);
  asm volatile("s_waitcnt vmcnt(0)" ::: "memory");
  COMPUTE(2*NC-1);

  const int col = nb + wv*16 + l15;
  const float bn = bias[col];
  #pragma unroll
  for (int mt = 0; mt < 4; ++mt)
    #pragma unroll
    for (int r = 0; r < 4; ++r){
      int m = mt*16 + lg*4 + r;
      C[(long)m * N + col] = acc[mt][r] + bn;
    }
}

// ---------------------------------------------------------------------------
// Fused prep: [0,8) hproj GEMM (direct f32 reads, +attn_b -> hpr),
// [8,4104) enc->bf16, [4104,4360) attn_w cvt, [4360,4376) emb gather,
// [4376,4408) hidden cvt, [4408,4412) scores zero.
// ---------------------------------------------------------------------------
__global__ __launch_bounds__(256) void prep_all(
    const int* __restrict__ tok, const float* __restrict__ emb,
    const float* __restrict__ hidden, const float* __restrict__ enc,
    const float* __restrict__ attn_w, const float* __restrict__ attn_b,
    short* __restrict__ encbf, short* __restrict__ Wbf,
    short* __restrict__ A0, short* __restrict__ A1, short* __restrict__ Zb,
    float* __restrict__ sco, float* __restrict__ hpr)
{
  const int bid = blockIdx.x, t = threadIdx.x;
  if (bid < 8){
    const int wv = t >> 6, lane = t & 63, l15 = lane & 15, lg = lane >> 4;
    const int nb = bid*64 + wv*16;
    const float* hrow = hidden + 65536;            // h_top [64][1024] f32
    const float* wrow = attn_w + (long)(nb + l15)*2048 + lg*8;
    f32x4 acc[4] = {};
    bf16x8 wn  = ld8_bf(wrow);
    bf16x8 an0 = ld8_bf(hrow + l15*1024 + lg*8);
    bf16x8 an1 = ld8_bf(hrow + (16+l15)*1024 + lg*8);
    bf16x8 an2 = ld8_bf(hrow + (32+l15)*1024 + lg*8);
    bf16x8 an3 = ld8_bf(hrow + (48+l15)*1024 + lg*8);
    for (int kb = 32; kb < 1024; kb += 32){
      bf16x8 wc = wn, c0 = an0, c1 = an1, c2 = an2, c3 = an3;
      wn  = ld8_bf(wrow + kb);
      an0 = ld8_bf(hrow + l15*1024 + lg*8 + kb);
      an1 = ld8_bf(hrow + (16+l15)*1024 + lg*8 + kb);
      an2 = ld8_bf(hrow + (32+l15)*1024 + lg*8 + kb);
      an3 = ld8_bf(hrow + (48+l15)*1024 + lg*8 + kb);
      acc[0] = __builtin_amdgcn_mfma_f32_16x16x32_bf16(c0, wc, acc[0], 0,0,0);
      acc[1] = __builtin_amdgcn_mfma_f32_16x16x32_bf16(c1, wc, acc[1], 0,0,0);
      acc[2] = __builtin_amdgcn_mfma_f32_16x16x32_bf16(c2, wc, acc[2], 0,0,0);
      acc[3] = __builtin_amdgcn_mfma_f32_16x16x32_bf16(c3, wc, acc[3], 0,0,0);
    }
    acc[0] = __builtin_amdgcn_mfma_f32_16x16x32_bf16(an0, wn, acc[0], 0,0,0);
    acc[1] = __builtin_amdgcn_mfma_f32_16x16x32_bf16(an1, wn, acc[1], 0,0,0);
    acc[2] = __builtin_amdgcn_mfma_f32_16x16x32_bf16(an2, wn, acc[2], 0,0,0);
    acc[3] = __builtin_amdgcn_mfma_f32_16x16x32_bf16(an3, wn, acc[3], 0,0,0);
    const float bn = attn_b[nb + l15];
    #pragma unroll
    for (int mt = 0; mt < 4; ++mt)
      #pragma unroll
      for (int r = 0; r < 4; ++r)
        hpr[(mt*16 + lg*4 + r)*512 + nb + l15] = acc[mt][r] + bn;
  } else if (bid < 4104){
    long i = ((long)(bid-8)*256 + t)*8;
    *(bf16x8*)(encbf + i) = ld8_bf(enc + i);
  } else if (bid < 4360){
    int j = (bid-4104)*256 + t;
    int r = j >> 7, c = (j & 127)*8;
    *(bf16x8*)(Wbf + r*1024 + c) = ld8_bf(attn_w + (long)r*2048 + 1024 + c);
  } else if (bid < 4376){
    int j = (bid-4360)*256 + t;
    int b = j >> 6, e8 = (j & 63)*8;
    bf16x8 v = ld8_bf(emb + (long)tok[b]*512 + e8);
    *(bf16x8*)(A0 + b*2560 + e8) = v;
    *(bf16x8*)(Zb + b*2560 + 2048 + e8) = v;
  } else if (bid < 4408){
    int j = (bid-4376)*256 + t;
    int b = j >> 7, n8 = (j & 127)*8;
    *(bf16x8*)(A0 + b*2560 + 1536 + n8) = ld8_bf(hidden + (long)b*1024 + n8);
    *(bf16x8*)(A1 + b*2048 + 1024 + n8) = ld8_bf(hidden + 65536 + (long)b*1024 + n8);
  } else {
    int j = (bid-4408)*256 + t;
    float4 z = {0.f, 0.f, 0.f, 0.f};
    *(float4*)(sco + j*8) = z;
    *(float4*)(sco + j*8 + 4) = z;
  }
}

// ---------------------------------------------------------------------------
// energy: T = encbf @ Wbf^T ; scores += v.tanh(T + hpr). Both operands
// streamed to LDS in 64-k chunks, 3-buffer rotation, counted vmcnt(4).
// grid 1024: m3 = bx&127 -> n-blocks of an m-tile share an XCD L2.
// ---------------------------------------------------------------------------
__global__ __launch_bounds__(256) void energy_lds(
    const short* __restrict__ encbf, const short* __restrict__ Wbf,
    const float* __restrict__ hpr, const float* __restrict__ v_w,
    float* __restrict__ scores)
{
  __shared__ short Ab[3][64*64];   // enc chunks, 24 KB
  __shared__ short Bb[3][64*64];   // Wbf chunks, 24 KB
  const int bx   = blockIdx.x;
  const int m3   = bx & 127, n3 = bx >> 7;
  const int wv   = threadIdx.x >> 6;
  const int lane = threadIdx.x & 63;
  const int l15  = lane & 15;
  const int lg   = lane >> 4;
  const int mb   = m3 * 64;
  const int nbg  = n3 * 64;
  const int nb   = nbg + wv * 16;
  const int b    = mb >> 7;

  const float hp = hpr[(long)b*512 + nb + l15];
  const float vn = v_w[nb + l15];

  const int srow = lane >> 3;
  const int scb  = (lane & 7) * 16;

  auto STAGE = [&](int c, int kb){
    short* da = Ab[c % 3];
    short* db = Bb[c % 3];
    #pragma unroll
    for (int i = 0; i < 2; ++i){
      int rbase = wv*16 + i*8;
      int row   = rbase + srow;
      int swz   = scb ^ ((row & 7) << 4);
      const char* sa = (const char*)(encbf + (long)(mb + row)*1024 + kb) + swz;
      stage16(sa, (void*)(da + rbase*64));
      const char* sb = (const char*)(Wbf + (long)(nbg + row)*1024 + kb) + swz;
      stage16(sb, (void*)(db + rbase*64));
    }
  };

  f32x4 acc[4] = {};
  const int brow = wv*16 + l15;
  const int bswz = (brow & 7) << 4;
  const int aswz = (l15 & 7) << 4;

  auto COMPUTE = [&](int c){
    const char* ab = (const char*)Ab[c % 3];
    const char* bb = (const char*)Bb[c % 3];
    #pragma unroll
    for (int h = 0; h < 2; ++h){
      const int colb = h*64 + lg*16;
      bf16x8 bf_ = *(const bf16x8*)(bb + brow*128 + (colb ^ bswz));
      #pragma unroll
      for (int m = 0; m < 4; ++m){
        const int arow = m*16 + l15;
        bf16x8 af = *(const bf16x8*)(ab + arow*128 + (colb ^ aswz));
        acc[m] = __builtin_amdgcn_mfma_f32_16x16x32_bf16(af, bf_, acc[m], 0,0,0);
      }
    }
  };

  STAGE(0, 0);
  STAGE(1, 64);
  for (int c = 0; c < 14; ++c){
    asm volatile("s_waitcnt vmcnt(4)" ::: "memory");
    __builtin_amdgcn_s_barrier();
    COMPUTE(c);
    STAGE(c+2, (c+2)*64);
  }
  asm volatile("s_waitcnt vmcnt(4)" ::: "memory");
  __builtin_amdgcn_s_barrier();
  COMPUTE(14);
  asm volatile("s_waitcnt vmcnt(0)" ::: "memory");
  __builtin_amdgcn_s_barrier();
  COMPUTE(15);

  #pragma unroll
  for (int mt = 0; mt < 4; ++mt){
    #pragma unroll
    for (int r = 0; r < 4; ++r){
      int m = mb + mt*16 + lg*4 + r;
      float e = fast_tanh(acc[mt][r] + hp) * vn;
      e += __shfl_xor(e, 1, 16);
      e += __shfl_xor(e, 2, 16);
      e += __shfl_xor(e, 4, 16);
      e += __shfl_xor(e, 8, 16);
      if (l15 == 0) atomicAdd(&scores[m], e);
    }
  }
}

// Fused masked softmax + context (ILP: 4 accumulators)
__global__ __launch_bounds__(256) void ctxsm_k(
    const float* __restrict__ sco, const int* __restrict__ mask,
    const short* __restrict__ encbf, float* __restrict__ aw,
    short* __restrict__ A0, short* __restrict__ Zb)
{
  const int bb = blockIdx.x;
  const int t  = threadIdx.x;
  __shared__ float red[128];
  __shared__ float w[128];
  float v = 0.f;
  if (t < 128){
    v = sco[bb*128 + t];
    if (mask[bb*128 + t] == 0) v = -1e10f;
    red[t] = v;
  }
  __syncthreads();
  for (int d = 64; d > 0; d >>= 1){
    if (t < d) red[t] = fmaxf(red[t], red[t + d]);
    __syncthreads();
  }
  const float mx = red[0];
  __syncthreads();
  if (t < 128){
    float e = __expf(v - mx);
    w[t] = e; red[t] = e;
  }
  __syncthreads();
  for (int d = 64; d > 0; d >>= 1){
    if (t < d) red[t] += red[t + d];
    __syncthreads();
  }
  const float inv = 1.f / red[0];
  if (blockIdx.y == 0 && t < 128) aw[bb*128 + t] = w[t] * inv;

  const int dd = blockIdx.y * 256 + t;
  const unsigned short* e = (const unsigned short*)encbf + (long)bb*131072 + dd;
  float s0 = 0.f, s1 = 0.f, s2 = 0.f, s3 = 0.f;
  #pragma unroll 8
  for (int si = 0; si < 128; si += 4){
    s0 += w[si  ] * __builtin_bit_cast(float, (unsigned)e[(si  )*1024] << 16);
    s1 += w[si+1] * __builtin_bit_cast(float, (unsigned)e[(si+1)*1024] << 16);
    s2 += w[si+2] * __builtin_bit_cast(float, (unsigned)e[(si+2)*1024] << 16);
    s3 += w[si+3] * __builtin_bit_cast(float, (unsigned)e[(si+3)*1024] << 16);
  }
  float s = ((s0 + s1) + (s2 + s3)) * inv;
  short vbf = f2bf(s);
  A0[bb*2560 + 512  + dd] = vbf;
  Zb[bb*2560 + 1024 + dd] = vbf;
}

// ---------------------------------------------------------------------------
// gates01: [0,640) gates0 slices (A0 @ [w_ih0|w_hh0] -> Pb planes 0..9);
//          [640,896) gates1 hidden-half (A1 k>=1024 @ w_hh1 -> Pb1 planes 4..7)
// Both depend only on prep/ctxsm outputs; per-block work identical.
// ---------------------------------------------------------------------------
__global__ __launch_bounds__(256) void gates01_k(
    const short* __restrict__ A0, const float* __restrict__ w_ih0,
    const float* __restrict__ w_hh0, float* __restrict__ Pb,
    const short* __restrict__ A1, const float* __restrict__ w_ih1,
    const float* __restrict__ w_hh1, float* __restrict__ Pb1)
{
  __shared__ char smem[81920];
  if (blockIdx.x < 640){
    int sl = blockIdx.x >> 6, ct = blockIdx.x & 63;
    gates_body(A0, 2560, w_ih0, 1536, 1536, w_hh0, 1024,
               Pb + (long)sl * 262144, 4096, ct * 64, sl * 256, smem);
  } else {
    int b2 = blockIdx.x - 640;
    int sl = 4 + (b2 >> 6), ct = b2 & 63;          // planes 4..7, k0 1024..2048
    gates_body(A1, 2048, w_ih1, 1024, 1024, w_hh1, 1024,
               Pb1 + (long)sl * 262144, 4096, ct * 64, sl * 256, smem);
  }
}

// gates1a: remaining layer-1 slices (k<1024, needs h0') -> Pb1 planes 0..3
__global__ __launch_bounds__(256) void gates1a_k(
    const short* __restrict__ A1, const float* __restrict__ w_ih1,
    float* __restrict__ Pb1)
{
  __shared__ char smem[81920];
  gates_body(A1, 2048, w_ih1, 1024, 1<<30, nullptr, 0,
             Pb1 + (long)blockIdx.y * 262144, 4096,
             blockIdx.x * 64, blockIdx.y * 256, smem);
}

// fc: full K=2560
__global__ __launch_bounds__(256) void fc_k(
    const short* __restrict__ Zb, const float* __restrict__ fc_w,
    const float* __restrict__ fc_b, float* __restrict__ pred)
{
  __shared__ char smem[81920];
  fc_body(Zb, 2560, fc_w, 2560, 20, fc_b, pred, 32000, blockIdx.x * 64, smem);
}

// LSTM epilogue with fused split-K reduce (KS templated)
template<int KS>
__global__ __launch_bounds__(256) void lstm_k(
    const float* __restrict__ P,
    const float* __restrict__ bi, const float* __restrict__ bh,
    const float* __restrict__ c_prev,
    float* __restrict__ h_out, float* __restrict__ c_out,
    short* __restrict__ h_bf, int bf_stride)
{
  const int i = blockIdx.x * 256 + threadIdx.x;
  const int b = i >> 10, n = i & 1023;
  float g4[4];
  #pragma unroll
  for (int gi = 0; gi < 4; ++gi){
    int col = gi*1024 + n;
    float s = bi[col] + bh[col];
    const float* p = P + (long)b*4096 + col;
    #pragma unroll
    for (int sl = 0; sl < KS; ++sl) s += p[(long)sl * 262144];
    g4[gi] = s;
  }
  float iv = fast_sig (g4[0]);
  float fv = fast_sig (g4[1]);
  float gv = fast_tanh(g4[2]);
  float ov = fast_sig (g4[3]);
  float c = fv * c_prev[i] + iv * gv;
  float h = ov * fast_tanh(c);
  c_out[i] = c;
  h_out[i] = h;
  h_bf[(long)b * bf_stride + n] = f2bf(h);
}

extern "C" void kernel_launch(void* const* d_in, const int* in_sizes, int n_in,
                              void* d_out, int out_size, void* d_ws, size_t ws_size,
                              hipStream_t stream)
{
  const int*   tok    = (const int*)  d_in[0];
  const float* hidden = (const float*)d_in[1];
  const float* cell   = (const float*)d_in[2];
  const float* enc    = (const float*)d_in[3];
  const int*   mask   = (const int*)  d_in[4];
  const float* emb    = (const float*)d_in[5];
  const float* attn_w = (const float*)d_in[6];
  const float* attn_b = (const float*)d_in[7];
  const float* v_w    = (const float*)d_in[8];
  const float* w_ih0  = (const float*)d_in[9];
  const float* w_hh0  = (const float*)d_in[10];
  const float* b_ih0  = (const float*)d_in[11];
  const float* b_hh0  = (const float*)d_in[12];
  const float* w_ih1  = (const float*)d_in[13];
  const float* w_hh1  = (const float*)d_in[14];
  const float* b_ih1  = (const float*)d_in[15];
  const float* b_hh1  = (const float*)d_in[16];
  const float* fc_w   = (const float*)d_in[17];
  const float* fc_b   = (const float*)d_in[18];

  float* out  = (float*)d_out;
  float* pred = out;                 // [64,32000]
  float* nh   = out + 2048000;       // [2,64,1024]
  float* nc   = out + 2179072;       // [2,64,1024]
  float* aw   = out + 2310144;       // [64,128]

  char*  wsb   = (char*)d_ws;
  short* encbf = (short*)(wsb + 0);          // 16,777,216 B
  short* Wbf   = (short*)(wsb + 16777216);   //  1,048,576 B
  short* A0    = (short*)(wsb + 17825792);   //    327,680 B
  short* A1    = (short*)(wsb + 18153472);   //    262,144 B
  short* Zb    = (short*)(wsb + 18415616);   //    327,680 B
  float* sco   = (float*)(wsb + 18743296);   //     32,768 B
  float* hpr   = (float*)(wsb + 18776064);   //    131,072 B
  float* Pb    = (float*)(wsb + 18907136);   // 10,485,760 B (gates0, 10 planes)
  float* Pb1   = (float*)(wsb + 29392896);   //  8,388,608 B (gates1, 8 planes)

  prep_all<<<4412, 256, 0, stream>>>(tok, emb, hidden, enc, attn_w, attn_b,
                                     encbf, Wbf, A0, A1, Zb, sco, hpr);

  energy_lds<<<1024, 256, 0, stream>>>(encbf, Wbf, hpr, v_w, sco);

  ctxsm_k<<<dim3(64, 4), 256, 0, stream>>>(sco, mask, encbf, aw, A0, Zb);

  // gates0 (10 slices) || gates1 hidden-half (4 slices)
  gates01_k<<<896, 256, 0, stream>>>(A0, w_ih0, w_hh0, Pb,
                                     A1, w_ih1, w_hh1, Pb1);

  lstm_k<10><<<256, 256, 0, stream>>>(Pb, b_ih0, b_hh0, cell,
                                      nh, nc, A1, 2048);

  // gates1 h0'-half (4 slices, k<1024)
  gates1a_k<<<dim3(64, 4), 256, 0, stream>>>(A1, w_ih1, Pb1);

  lstm_k<8><<<256, 256, 0, stream>>>(Pb1, b_ih1, b_hh1, cell + 65536,
                                     nh + 65536, nc + 65536, Zb, 2560);

  // prediction = Zb @ fc_w^T + fc_b
  fc_k<<<500, 256, 0, stream>>>(Zb, fc_w, fc_b, pred);
}

// Round 16
// 146.150 us; speedup vs baseline: 1.1997x; 1.1614x over previous
//
#include <hip/hip_runtime.h>

// Decoder step: embed -> additive attention -> 2-layer LSTM -> fc
// Round 16: exact r13 structure (best, 147us), one change: energy_lds runs
// 512 blocks x 2 n-tiles (single occupancy round at 3 blk/CU, no 2nd-round
// drain; enc rows L2-hot for the 2nd tile). Everything else = r13.

typedef __attribute__((ext_vector_type(8))) short bf16x8;
typedef __attribute__((ext_vector_type(4))) float f32x4;

__device__ __forceinline__ short f2bf(float f){
  __bf16 h = (__bf16)f;
  return __builtin_bit_cast(short, h);
}

__device__ __forceinline__ bf16x8 cvt8(float4 a, float4 b){
  bf16x8 r;
  r[0]=f2bf(a.x); r[1]=f2bf(a.y); r[2]=f2bf(a.z); r[3]=f2bf(a.w);
  r[4]=f2bf(b.x); r[5]=f2bf(b.y); r[6]=f2bf(b.z); r[7]=f2bf(b.w);
  return r;
}

__device__ __forceinline__ bf16x8 ld8_bf(const float* __restrict__ p){
  return cvt8(*(const float4*)p, *(const float4*)(p + 4));
}

__device__ __forceinline__ float fast_tanh(float x){
  x = fminf(fmaxf(x, -15.f), 15.f);
  float t = __expf(2.f * x);
  return (t - 1.f) / (t + 1.f);
}
__device__ __forceinline__ float fast_sig(float x){
  return 1.f / (1.f + __expf(-x));
}

__device__ __forceinline__ void stage16(const void* src, void* dst_lds){
  __builtin_amdgcn_global_load_lds(
      (const __attribute__((address_space(1))) void*)src,
      (__attribute__((address_space(3))) void*)dst_lds, 16, 0, 0);
}

// ---------------------------------------------------------------------------
// Fused prep: enc->bf16, attn_w[:,1024:2048]->bf16, emb gather, hidden cvt,
// scores zero.
// ---------------------------------------------------------------------------
__global__ __launch_bounds__(256) void prep_all(
    const int* __restrict__ tok, const float* __restrict__ emb,
    const float* __restrict__ hidden, const float* __restrict__ enc,
    const float* __restrict__ attn_w,
    short* __restrict__ encbf, short* __restrict__ Wbf,
    short* __restrict__ A0, short* __restrict__ A1, short* __restrict__ Zb,
    float* __restrict__ sco)
{
  const int bid = blockIdx.x, t = threadIdx.x;
  if (bid < 4096){
    long i = ((long)bid*256 + t)*8;
    *(bf16x8*)(encbf + i) = ld8_bf(enc + i);
  } else if (bid < 4352){
    int j = (bid-4096)*256 + t;
    int r = j >> 7, c = (j & 127)*8;
    *(bf16x8*)(Wbf + r*1024 + c) = ld8_bf(attn_w + (long)r*2048 + 1024 + c);
  } else if (bid < 4368){
    int j = (bid-4352)*256 + t;
    int b = j >> 6, e8 = (j & 63)*8;
    bf16x8 v = ld8_bf(emb + (long)tok[b]*512 + e8);
    *(bf16x8*)(A0 + b*2560 + e8) = v;
    *(bf16x8*)(Zb + b*2560 + 2048 + e8) = v;
  } else if (bid < 4400){
    int j = (bid-4368)*256 + t;
    int b = j >> 7, n8 = (j & 127)*8;
    *(bf16x8*)(A0 + b*2560 + 1536 + n8) = ld8_bf(hidden + (long)b*1024 + n8);
    *(bf16x8*)(A1 + b*2048 + 1024 + n8) = ld8_bf(hidden + 65536 + (long)b*1024 + n8);
  } else {
    int j = (bid-4400)*256 + t;
    float4 z = {0.f, 0.f, 0.f, 0.f};
    *(float4*)(sco + j*8) = z;
    *(float4*)(sco + j*8 + 4) = z;
  }
}

// ---------------------------------------------------------------------------
// P[by][64][N] = A_bf16[64,K] @ [W1|W2][N,:]^T on a 256-wide k-slice.
// ---------------------------------------------------------------------------
#define KSL 256
__global__ __launch_bounds__(256) void gemm_lds(
    const short* __restrict__ A, int lda,
    const float* __restrict__ W1, int sW1, int K1,
    const float* __restrict__ W2, int sW2,
    float* __restrict__ P, int N)
{
  __shared__ short Al[64*256];     // 32 KB
  __shared__ float Wl[3][64*64];   // 48 KB
  const int wv   = threadIdx.x >> 6;
  const int lane = threadIdx.x & 63;
  const int l15  = lane & 15;
  const int lg   = lane >> 4;
  const int nb   = blockIdx.x * 64;
  const int k0   = blockIdx.y * KSL;

  const float* W; int sW, koff;
  if (k0 < K1){ W = W1; sW = sW1; koff = k0; }
  else        { W = W2; sW = sW2; koff = k0 - K1; }

  {
    const int r2  = lane >> 5;
    const int c16 = (lane & 31) * 16;
    #pragma unroll
    for (int i = 0; i < 8; ++i){
      int rbase = wv*16 + i*2;
      int row   = rbase + r2;
      const char* src = (const char*)A + (long)row*lda*2 + (long)k0*2
                        + (c16 ^ ((row & 7) << 4));
      stage16(src, (void*)(Al + rbase*256));
    }
  }

  auto STAGEW = [&](int bi, int kbase){
    #pragma unroll
    for (int i = 0; i < 4; ++i){
      int row = wv*16 + i*4 + lg;
      const char* src = (const char*)(W + (long)(nb + row)*sW + koff + kbase)
                        + ((l15*16) ^ ((row & 7) << 4));
      stage16(src, (void*)&Wl[bi][(wv*16 + i*4)*64]);
    }
  };

  STAGEW(0, 0);
  STAGEW(1, 64);
  asm volatile("s_waitcnt vmcnt(8)" ::: "memory");
  asm volatile("s_barrier" ::: "memory");

  f32x4 acc[4];
  #pragma unroll
  for (int m = 0; m < 4; ++m) acc[m] = (f32x4){0.f,0.f,0.f,0.f};

  const int  rl = wv*16 + l15;
  const int  sw = (l15 & 7) << 4;
  const char* wbase = (const char*)&Wl[0][0];
  const char* abase = (const char*)Al;

  auto COMPUTE = [&](int bi, int t){
    bf16x8 a[4][2];
    #pragma unroll
    for (int m = 0; m < 4; ++m)
      #pragma unroll
      for (int h = 0; h < 2; ++h){
        int cb = t*128 + h*64 + lg*16;
        a[m][h] = *(const bf16x8*)(abase + (m*16 + l15)*512 + (cb ^ sw));
      }
    const char* rb = wbase + bi*16384 + rl*256;
    float4 w00 = *(const float4*)(rb + ((lg*32      ) ^ sw));
    float4 w01 = *(const float4*)(rb + ((lg*32 + 16 ) ^ sw));
    float4 w10 = *(const float4*)(rb + ((lg*32 + 128) ^ sw));
    float4 w11 = *(const float4*)(rb + ((lg*32 + 144) ^ sw));
    bf16x8 wf0 = cvt8(w00, w01);
    bf16x8 wf1 = cvt8(w10, w11);
    #pragma unroll
    for (int m = 0; m < 4; ++m)
      acc[m] = __builtin_amdgcn_mfma_f32_16x16x32_bf16(a[m][0], wf0, acc[m], 0,0,0);
    #pragma unroll
    for (int m = 0; m < 4; ++m)
      acc[m] = __builtin_amdgcn_mfma_f32_16x16x32_bf16(a[m][1], wf1, acc[m], 0,0,0);
  };

  asm volatile("s_waitcnt vmcnt(4)" ::: "memory");
  COMPUTE(0, 0);
  STAGEW(2, 128);
  asm volatile("s_waitcnt vmcnt(4)" ::: "memory");
  COMPUTE(1, 1);
  STAGEW(0, 192);
  asm volatile("s_waitcnt vmcnt(4)" ::: "memory");
  COMPUTE(2, 2);
  asm volatile("s_waitcnt vmcnt(0)" ::: "memory");
  COMPUTE(0, 3);

  float* p = P + (long)blockIdx.y * 64 * N;
  #pragma unroll
  for (int mt = 0; mt < 4; ++mt)
    #pragma unroll
    for (int r = 0; r < 4; ++r){
      int m = mt*16 + lg*4 + r;
      p[(long)m * N + nb + wv*16 + l15] = acc[mt][r];
    }
}

// ---------------------------------------------------------------------------
// fc: C[64,N] = A[64,2560] @ W[N,2560]^T + bias. Full K, 2 blocks/CU,
// per-wave-private W streams, A double-buffered per 128-k chunk.
// ---------------------------------------------------------------------------
__global__ __launch_bounds__(256) void gemm_fc2(
    const short* __restrict__ A, int lda,
    const float* __restrict__ W, int sW,
    const float* __restrict__ bias,
    float* __restrict__ C, int N)
{
  __shared__ short Al[2][64*128];   // 2 x 16 KB
  __shared__ float Wl[3][64*64];    // 3 x 16 KB
  const int wv   = threadIdx.x >> 6;
  const int lane = threadIdx.x & 63;
  const int l15  = lane & 15;
  const int lg   = lane >> 4;
  const int nb   = blockIdx.x * 64;

  auto STAGEA = [&](int c){
    short* dst = Al[c & 1];
    #pragma unroll
    for (int i = 0; i < 4; ++i){
      int rbase = wv*16 + i*4;
      int row   = rbase + lg;
      const char* src = (const char*)(A + (long)row*lda + c*128)
                        + ((l15*16) ^ ((row & 7) << 4));
      stage16(src, (void*)(dst + rbase*128));
    }
  };
  auto STAGEW = [&](int s){
    float* dst = Wl[s % 3];
    #pragma unroll
    for (int i = 0; i < 4; ++i){
      int row = wv*16 + i*4 + lg;
      const char* src = (const char*)(W + (long)(nb + row)*sW + s*64)
                        + ((l15*16) ^ ((row & 7) << 4));
      stage16(src, (void*)(dst + (wv*16 + i*4)*64));
    }
  };

  f32x4 acc[4];
  #pragma unroll
  for (int m = 0; m < 4; ++m) acc[m] = (f32x4){0.f,0.f,0.f,0.f};

  const int rl = wv*16 + l15;
  const int sw = (l15 & 7) << 4;

  auto COMPUTE = [&](int s){
    const char* abase = (const char*)Al[(s >> 1) & 1];
    const int   kh    = (s & 1) * 128;
    bf16x8 a[4][2];
    #pragma unroll
    for (int m = 0; m < 4; ++m)
      #pragma unroll
      for (int h = 0; h < 2; ++h){
        int cb = kh + h*64 + lg*16;
        a[m][h] = *(const bf16x8*)(abase + (m*16 + l15)*256 + (cb ^ sw));
      }
    const char* rb = (const char*)Wl[s % 3] + rl*256;
    float4 w00 = *(const float4*)(rb + ((lg*32      ) ^ sw));
    float4 w01 = *(const float4*)(rb + ((lg*32 + 16 ) ^ sw));
    float4 w10 = *(const float4*)(rb + ((lg*32 + 128) ^ sw));
    float4 w11 = *(const float4*)(rb + ((lg*32 + 144) ^ sw));
    bf16x8 wf0 = cvt8(w00, w01);
    bf16x8 wf1 = cvt8(w10, w11);
    #pragma unroll
    for (int m = 0; m < 4; ++m)
      acc[m] = __builtin_amdgcn_mfma_f32_16x16x32_bf16(a[m][0], wf0, acc[m], 0,0,0);
    #pragma unroll
    for (int m = 0; m < 4; ++m)
      acc[m] = __builtin_amdgcn_mfma_f32_16x16x32_bf16(a[m][1], wf1, acc[m], 0,0,0);
  };

  STAGEA(0); STAGEW(0); STAGEW(1);
  asm volatile("s_waitcnt vmcnt(4)" ::: "memory");
  __builtin_amdgcn_s_barrier();

  STAGEA(1);
  COMPUTE(0);
  STAGEW(2);
  asm volatile("s_waitcnt vmcnt(4)" ::: "memory");
  COMPUTE(1);
  STAGEW(3);
  __builtin_amdgcn_s_barrier();

  for (int c = 1; c < 19; ++c){
    STAGEA(c+1);
    asm volatile("s_waitcnt vmcnt(8)" ::: "memory");
    COMPUTE(2*c);
    STAGEW(2*c+2);
    asm volatile("s_waitcnt vmcnt(4)" ::: "memory");
    COMPUTE(2*c+1);
    STAGEW(2*c+3);
    __builtin_amdgcn_s_barrier();
  }

  asm volatile("s_waitcnt vmcnt(4)" ::: "memory");
  COMPUTE(38);
  asm volatile("s_waitcnt vmcnt(0)" ::: "memory");
  COMPUTE(39);

  const int col = nb + wv*16 + l15;
  const float bn = bias[col];
  #pragma unroll
  for (int mt = 0; mt < 4; ++mt)
    #pragma unroll
    for (int r = 0; r < 4; ++r){
      int m = mt*16 + lg*4 + r;
      C[(long)m * N + col] = acc[mt][r] + bn;
    }
}

// ---------------------------------------------------------------------------
// energy: T = encbf @ Wbf^T ; scores += v.tanh(T + hproj). 512 blocks x 2
// n-tiles (vt = bid, bid+512): same m-tile both times (enc L2-hot), single
// occupancy round at 3 blocks/CU. LDS pipeline per tile: 64-k chunks,
// 3-buffer rotation, counted vmcnt(4), barrier per chunk.
// ---------------------------------------------------------------------------
__global__ __launch_bounds__(256) void energy_lds(
    const short* __restrict__ encbf, const short* __restrict__ Wbf,
    const float* __restrict__ Ph, const float* __restrict__ attn_b,
    const float* __restrict__ v_w, float* __restrict__ scores)
{
  __shared__ short Ab[3][64*64];   // enc chunks, 24 KB
  __shared__ short Bb[3][64*64];   // Wbf chunks, 24 KB
  const int wv   = threadIdx.x >> 6;
  const int lane = threadIdx.x & 63;
  const int l15  = lane & 15;
  const int lg   = lane >> 4;

  const int srow = lane >> 3;
  const int scb  = (lane & 7) * 16;
  const int brow = wv*16 + l15;
  const int bswz = (brow & 7) << 4;
  const int aswz = (l15 & 7) << 4;

  #pragma unroll
  for (int e = 0; e < 2; ++e){
    const int vt = blockIdx.x + e*512;
    const int m3 = vt & 127, n3 = vt >> 7;
    const int mb  = m3 * 64;
    const int nbg = n3 * 64;
    const int nb  = nbg + wv * 16;
    const int b   = mb >> 7;

    const int hi = b*512 + nb + l15;
    const float hp = attn_b[nb + l15] + Ph[hi] + Ph[32768 + hi]
                   + Ph[65536 + hi] + Ph[98304 + hi];
    const float vn = v_w[nb + l15];

    auto STAGE = [&](int c, int kb){
      short* da = Ab[c % 3];
      short* db = Bb[c % 3];
      #pragma unroll
      for (int i = 0; i < 2; ++i){
        int rbase = wv*16 + i*8;
        int row   = rbase + srow;
        int swz   = scb ^ ((row & 7) << 4);
        const char* sa = (const char*)(encbf + (long)(mb + row)*1024 + kb) + swz;
        stage16(sa, (void*)(da + rbase*64));
        const char* sb = (const char*)(Wbf + (long)(nbg + row)*1024 + kb) + swz;
        stage16(sb, (void*)(db + rbase*64));
      }
    };

    f32x4 acc[4] = {};
    auto COMPUTE = [&](int c){
      const char* ab = (const char*)Ab[c % 3];
      const char* bb = (const char*)Bb[c % 3];
      #pragma unroll
      for (int h = 0; h < 2; ++h){
        const int colb = h*64 + lg*16;
        bf16x8 bf_ = *(const bf16x8*)(bb + brow*128 + (colb ^ bswz));
        #pragma unroll
        for (int m = 0; m < 4; ++m){
          const int arow = m*16 + l15;
          bf16x8 af = *(const bf16x8*)(ab + arow*128 + (colb ^ aswz));
          acc[m] = __builtin_amdgcn_mfma_f32_16x16x32_bf16(af, bf_, acc[m], 0,0,0);
        }
      }
    };

    if (e) __builtin_amdgcn_s_barrier();   // buffer reuse guard across tiles
    STAGE(0, 0);
    STAGE(1, 64);
    for (int c = 0; c < 14; ++c){
      asm volatile("s_waitcnt vmcnt(4)" ::: "memory");
      __builtin_amdgcn_s_barrier();
      COMPUTE(c);
      STAGE(c+2, (c+2)*64);
    }
    asm volatile("s_waitcnt vmcnt(4)" ::: "memory");
    __builtin_amdgcn_s_barrier();
    COMPUTE(14);
    asm volatile("s_waitcnt vmcnt(0)" ::: "memory");
    __builtin_amdgcn_s_barrier();
    COMPUTE(15);

    #pragma unroll
    for (int mt = 0; mt < 4; ++mt){
      #pragma unroll
      for (int r = 0; r < 4; ++r){
        int m = mb + mt*16 + lg*4 + r;
        float ev = fast_tanh(acc[mt][r] + hp) * vn;
        ev += __shfl_xor(ev, 1, 16);
        ev += __shfl_xor(ev, 2, 16);
        ev += __shfl_xor(ev, 4, 16);
        ev += __shfl_xor(ev, 8, 16);
        if (l15 == 0) atomicAdd(&scores[m], ev);
      }
    }
  }
}

// Fused masked softmax + context (ILP: 4 accumulators)
__global__ __launch_bounds__(256) void ctxsm_k(
    const float* __restrict__ sco, const int* __restrict__ mask,
    const short* __restrict__ encbf, float* __restrict__ aw,
    short* __restrict__ A0, short* __restrict__ Zb)
{
  const int bb = blockIdx.x;
  const int t  = threadIdx.x;
  __shared__ float red[128];
  __shared__ float w[128];
  float v = 0.f;
  if (t < 128){
    v = sco[bb*128 + t];
    if (mask[bb*128 + t] == 0) v = -1e10f;
    red[t] = v;
  }
  __syncthreads();
  for (int d = 64; d > 0; d >>= 1){
    if (t < d) red[t] = fmaxf(red[t], red[t + d]);
    __syncthreads();
  }
  const float mx = red[0];
  __syncthreads();
  if (t < 128){
    float e = __expf(v - mx);
    w[t] = e; red[t] = e;
  }
  __syncthreads();
  for (int d = 64; d > 0; d >>= 1){
    if (t < d) red[t] += red[t + d];
    __syncthreads();
  }
  const float inv = 1.f / red[0];
  if (blockIdx.y == 0 && t < 128) aw[bb*128 + t] = w[t] * inv;

  const int dd = blockIdx.y * 256 + t;
  const unsigned short* e = (const unsigned short*)encbf + (long)bb*131072 + dd;
  float s0 = 0.f, s1 = 0.f, s2 = 0.f, s3 = 0.f;
  #pragma unroll 8
  for (int si = 0; si < 128; si += 4){
    s0 += w[si  ] * __builtin_bit_cast(float, (unsigned)e[(si  )*1024] << 16);
    s1 += w[si+1] * __builtin_bit_cast(float, (unsigned)e[(si+1)*1024] << 16);
    s2 += w[si+2] * __builtin_bit_cast(float, (unsigned)e[(si+2)*1024] << 16);
    s3 += w[si+3] * __builtin_bit_cast(float, (unsigned)e[(si+3)*1024] << 16);
  }
  float s = ((s0 + s1) + (s2 + s3)) * inv;
  short vbf = f2bf(s);
  A0[bb*2560 + 512  + dd] = vbf;
  Zb[bb*2560 + 1024 + dd] = vbf;
}

// LSTM epilogue with fused split-K reduce (KS templated -> full unroll)
template<int KS>
__global__ __launch_bounds__(256) void lstm_k(
    const float* __restrict__ P,
    const float* __restrict__ bi, const float* __restrict__ bh,
    const float* __restrict__ c_prev,
    float* __restrict__ h_out, float* __restrict__ c_out,
    short* __restrict__ h_bf, int bf_stride)
{
  const int i = blockIdx.x * 256 + threadIdx.x;
  const int b = i >> 10, n = i & 1023;
  float g4[4];
  #pragma unroll
  for (int gi = 0; gi < 4; ++gi){
    int col = gi*1024 + n;
    float s = bi[col] + bh[col];
    const float* p = P + (long)b*4096 + col;
    #pragma unroll
    for (int sl = 0; sl < KS; ++sl) s += p[(long)sl * 262144];
    g4[gi] = s;
  }
  float iv = fast_sig (g4[0]);
  float fv = fast_sig (g4[1]);
  float gv = fast_tanh(g4[2]);
  float ov = fast_sig (g4[3]);
  float c = fv * c_prev[i] + iv * gv;
  float h = ov * fast_tanh(c);
  c_out[i] = c;
  h_out[i] = h;
  h_bf[(long)b * bf_stride + n] = f2bf(h);
}

extern "C" void kernel_launch(void* const* d_in, const int* in_sizes, int n_in,
                              void* d_out, int out_size, void* d_ws, size_t ws_size,
                              hipStream_t stream)
{
  const int*   tok    = (const int*)  d_in[0];
  const float* hidden = (const float*)d_in[1];
  const float* cell   = (const float*)d_in[2];
  const float* enc    = (const float*)d_in[3];
  const int*   mask   = (const int*)  d_in[4];
  const float* emb    = (const float*)d_in[5];
  const float* attn_w = (const float*)d_in[6];
  const float* attn_b = (const float*)d_in[7];
  const float* v_w    = (const float*)d_in[8];
  const float* w_ih0  = (const float*)d_in[9];
  const float* w_hh0  = (const float*)d_in[10];
  const float* b_ih0  = (const float*)d_in[11];
  const float* b_hh0  = (const float*)d_in[12];
  const float* w_ih1  = (const float*)d_in[13];
  const float* w_hh1  = (const float*)d_in[14];
  const float* b_ih1  = (const float*)d_in[15];
  const float* b_hh1  = (const float*)d_in[16];
  const float* fc_w   = (const float*)d_in[17];
  const float* fc_b   = (const float*)d_in[18];

  float* out  = (float*)d_out;
  float* pred = out;                 // [64,32000]
  float* nh   = out + 2048000;       // [2,64,1024]
  float* nc   = out + 2179072;       // [2,64,1024]
  float* aw   = out + 2310144;       // [64,128]

  char*  wsb   = (char*)d_ws;
  short* encbf = (short*)(wsb + 0);          // 16,777,216 B
  short* Wbf   = (short*)(wsb + 16777216);   //  1,048,576 B
  short* A0    = (short*)(wsb + 17825792);   //    327,680 B
  short* A1    = (short*)(wsb + 18153472);   //    262,144 B
  short* Zb    = (short*)(wsb + 18415616);   //    327,680 B
  float* sco   = (float*)(wsb + 18743296);   //     32,768 B
  float* Pb    = (float*)(wsb + 18776064);   // partials (hproj 4 / gates 10)

  prep_all<<<4404, 256, 0, stream>>>(tok, emb, hidden, enc, attn_w,
                                     encbf, Wbf, A0, A1, Zb, sco);

  // hproj partials = h_top @ attn_w[:,0:1024]^T  (4 x 256-k slices)
  gemm_lds<<<dim3(8, 4), 256, 0, stream>>>(A1 + 1024, 2048,
                                           attn_w, 2048, 1<<30, nullptr, 0,
                                           Pb, 512);

  energy_lds<<<512, 256, 0, stream>>>(encbf, Wbf, Pb, attn_b, v_w, sco);

  ctxsm_k<<<dim3(64, 4), 256, 0, stream>>>(sco, mask, encbf, aw, A0, Zb);

  // layer 0: A0 = [emb | ctx | h0_prev], W = [w_ih0 | w_hh0], K=2560
  gemm_lds<<<dim3(64, 10), 256, 0, stream>>>(A0, 2560,
                                             w_ih0, 1536, 1536, w_hh0, 1024,
                                             Pb, 4096);
  lstm_k<10><<<256, 256, 0, stream>>>(Pb, b_ih0, b_hh0, cell,
                                      nh, nc, A1, 2048);

  // layer 1: A1 = [h0' | h1_prev], W = [w_ih1 | w_hh1], K=2048
  gemm_lds<<<dim3(64, 8), 256, 0, stream>>>(A1, 2048,
                                            w_ih1, 1024, 1024, w_hh1, 1024,
                                            Pb, 4096);
  lstm_k<8><<<256, 256, 0, stream>>>(Pb, b_ih1, b_hh1, cell + 65536,
                                     nh + 65536, nc + 65536, Zb, 2560);

  // prediction = Zb @ fc_w^T + fc_b
  gemm_fc2<<<500, 256, 0, stream>>>(Zb, 2560, fc_w, 2560, fc_b, pred, 32000);
}